// Round 1
// baseline (264.040 us; speedup 1.0000x reference)
//
#include <hip/hip_runtime.h>
#include <cstdint>
#include <cstddef>

// Problem constants
#define B_N 65536
#define D_N 256
#define W_N 1024

typedef __bf16 bf16x8 __attribute__((ext_vector_type(8)));
typedef float f32x4 __attribute__((ext_vector_type(4)));
typedef unsigned short u16x8 __attribute__((ext_vector_type(8)));

__device__ __forceinline__ unsigned short f2bf(float f) {
  // round-to-nearest-even f32 -> bf16 (no NaN in this problem)
  unsigned u = __float_as_uint(f);
  u += 0x7fffu + ((u >> 16) & 1u);
  return (unsigned short)(u >> 16);
}

// ---------------------------------------------------------------------------
// Prep: cast W1 [1024x256] and W2 [256x1024] to bf16; M[j] = sum_i W1[j,i]*W2[i,j]
// grid 1024 blocks x 256 threads; block j handles 256 elements of each cast + M[j]
// ---------------------------------------------------------------------------
__global__ __launch_bounds__(256) void prep_kernel(
    const float* __restrict__ W1, const float* __restrict__ W2,
    unsigned short* __restrict__ W1b, unsigned short* __restrict__ W2b,
    float* __restrict__ M) {
  const int j = blockIdx.x;    // 0..1023
  const int t = threadIdx.x;   // 0..255
  const int gid = j * 256 + t; // covers 262144 exactly
  float w1 = W1[gid];
  float w2g = W2[gid];
  W1b[gid] = f2bf(w1);
  W2b[gid] = f2bf(w2g);
  // M[j]: thread t contributes W1[j,t] * W2[t,j]
  float p = w1 * W2[t * W_N + j];
  #pragma unroll
  for (int m = 32; m; m >>= 1) p += __shfl_xor(p, m);
  __shared__ float red[4];
  if ((t & 63) == 0) red[t >> 6] = p;
  __syncthreads();
  if (t == 0) M[j] = red[0] + red[1] + red[2] + red[3];
}

// ---------------------------------------------------------------------------
// Fused flow kernel. BM=64 rows/block, 4 waves, chunked over W in 4x256.
// LDS: z and h in "fragment-linear" blocked bf16 layout:
//   element (m,k) -> 16B slot ((k/32)*4 + m/16)*64 + ((k%32)/8)*16 + (m%16),
//   byte within slot = (k%8)*2.  A-frag read for (ks,tm) = base + lane*16B.
// MFMA 16x16x32 bf16: A[m=lane&15][k=(lane>>4)*8+j]; C row=(lane>>4)*4+reg, col=lane&15.
// ---------------------------------------------------------------------------
__global__ __launch_bounds__(256, 2) void flow_kernel(
    const float* __restrict__ z, const float* __restrict__ b1,
    const unsigned short* __restrict__ W1b, const unsigned short* __restrict__ W2b,
    const float* __restrict__ M, float* __restrict__ dz, float* __restrict__ tr) {
  __shared__ __align__(16) unsigned short z_sh[64 * 256]; // 32 KB
  __shared__ __align__(16) unsigned short h_sh[64 * 256]; // 32 KB

  const int tid = threadIdx.x;
  const int wave = tid >> 6;
  const int lane = tid & 63;
  const int l15 = lane & 15;
  const int q = lane >> 4; // quad 0..3
  const int row0 = blockIdx.x * 64;

  // ---- stage z tile [64 x 256] f32 -> bf16 blocked layout ----
  #pragma unroll
  for (int it = 0; it < 8; ++it) {
    int id = it * 256 + tid;
    int m = id >> 5;  // row 0..63
    int o = id & 31;  // octet of 8 floats
    const float* gp = z + (size_t)(row0 + m) * D_N + o * 8;
    f32x4 a = *(const f32x4*)gp;
    f32x4 b = *(const f32x4*)(gp + 4);
    u16x8 v;
    v[0] = f2bf(a[0]); v[1] = f2bf(a[1]); v[2] = f2bf(a[2]); v[3] = f2bf(a[3]);
    v[4] = f2bf(b[0]); v[5] = f2bf(b[1]); v[6] = f2bf(b[2]); v[7] = f2bf(b[3]);
    // k = o*8: ks = o>>2, qq = o&3; slot = ((ks*4 + m/16)*64 + qq*16 + m%16)
    int slot = (((o >> 2) * 4 + (m >> 4)) * 64 + (o & 3) * 16 + (m & 15));
    *(u16x8*)(z_sh + slot * 8) = v;
  }
  __syncthreads();

  f32x4 acc2[4][4]; // dz accumulator: [tm][tn], wave cols = wave*64 + tn*16 + l15
  #pragma unroll
  for (int a = 0; a < 4; ++a)
    #pragma unroll
    for (int b = 0; b < 4; ++b)
      acc2[a][b] = (f32x4){0.f, 0.f, 0.f, 0.f};
  float trp[4][4]; // trace partial per (tm, reg): row = tm*16 + q*4 + r
  #pragma unroll
  for (int a = 0; a < 4; ++a)
    #pragma unroll
    for (int r = 0; r < 4; ++r) trp[a][r] = 0.f;

  #pragma unroll 1
  for (int c = 0; c < 4; ++c) {
    const int j0 = c * 256;

    // ---- GEMM1: pre[64 x 256chunk] = z_tile @ W1[j0+..]^T, K = 256 ----
    f32x4 acc1[4][4];
    #pragma unroll
    for (int a = 0; a < 4; ++a)
      #pragma unroll
      for (int b = 0; b < 4; ++b)
        acc1[a][b] = (f32x4){0.f, 0.f, 0.f, 0.f};

    #pragma unroll
    for (int ks = 0; ks < 8; ++ks) {
      bf16x8 afr[4];
      #pragma unroll
      for (int tm = 0; tm < 4; ++tm)
        afr[tm] = *(const bf16x8*)(z_sh + ((ks * 4 + tm) * 64 + lane) * 8);
      bf16x8 bfr[4];
      #pragma unroll
      for (int tn = 0; tn < 4; ++tn)
        bfr[tn] = *(const bf16x8*)(W1b +
            (size_t)(j0 + wave * 64 + tn * 16 + l15) * D_N + ks * 32 + q * 8);
      #pragma unroll
      for (int tm = 0; tm < 4; ++tm)
        #pragma unroll
        for (int tn = 0; tn < 4; ++tn)
          acc1[tm][tn] = __builtin_amdgcn_mfma_f32_16x16x32_bf16(
              afr[tm], bfr[tn], acc1[tm][tn], 0, 0, 0);
    }

    __syncthreads(); // all waves done reading h_sh from previous chunk's GEMM2

    // ---- epilogue: softplus -> h_sh (blocked layout), sigmoid*M -> trace partials
    #pragma unroll
    for (int tn = 0; tn < 4; ++tn) {
      const int jl = wave * 64 + tn * 16 + l15; // chunk-local j, 0..255
      const int jg = j0 + jl;
      const float b1v = b1[jg];
      const float Mv = M[jg];
      const int slot_base = ((jl >> 5) * 4) * 64 + ((jl >> 3) & 3) * 16;
      const int byte_lo = (jl & 7);
      #pragma unroll
      for (int tm = 0; tm < 4; ++tm) {
        #pragma unroll
        for (int r = 0; r < 4; ++r) {
          float x = acc1[tm][tn][r] + b1v;
          float e = __expf(-fabsf(x));
          float inv = __builtin_amdgcn_rcpf(1.0f + e);
          float sig = (x >= 0.f) ? inv : (1.0f - inv);
          float sp = fmaxf(x, 0.f) + __logf(1.0f + e);
          trp[tm][r] += sig * Mv;
          int slot = slot_base + tm * 64 + (q * 4 + r); // row = tm*16 + q*4 + r
          h_sh[slot * 8 + byte_lo] = f2bf(sp);
        }
      }
    }
    __syncthreads(); // h_sh ready

    // ---- GEMM2: dz += h_chunk[64 x 256] @ W2[:, j0+..]^T, K = 256 ----
    #pragma unroll
    for (int ks = 0; ks < 8; ++ks) {
      bf16x8 afr[4];
      #pragma unroll
      for (int tm = 0; tm < 4; ++tm)
        afr[tm] = *(const bf16x8*)(h_sh + ((ks * 4 + tm) * 64 + lane) * 8);
      bf16x8 bfr[4];
      #pragma unroll
      for (int tn = 0; tn < 4; ++tn)
        bfr[tn] = *(const bf16x8*)(W2b +
            (size_t)(wave * 64 + tn * 16 + l15) * W_N + j0 + ks * 32 + q * 8);
      #pragma unroll
      for (int tm = 0; tm < 4; ++tm)
        #pragma unroll
        for (int tn = 0; tn < 4; ++tn)
          acc2[tm][tn] = __builtin_amdgcn_mfma_f32_16x16x32_bf16(
              afr[tm], bfr[tn], acc2[tm][tn], 0, 0, 0);
    }
  }

  // ---- store dz: out[(row0 + tm*16 + q*4 + r) * 256 + wave*64 + tn*16 + l15] ----
  #pragma unroll
  for (int tm = 0; tm < 4; ++tm)
    #pragma unroll
    for (int tn = 0; tn < 4; ++tn)
      #pragma unroll
      for (int r = 0; r < 4; ++r)
        dz[(size_t)(row0 + tm * 16 + q * 4 + r) * D_N + wave * 64 + tn * 16 + l15] =
            acc2[tm][tn][r];

  // ---- trace: reduce across the 16 lanes of each quad (cols), atomicAdd -sum ----
  #pragma unroll
  for (int tm = 0; tm < 4; ++tm) {
    #pragma unroll
    for (int r = 0; r < 4; ++r) {
      float v = trp[tm][r];
      v += __shfl_xor(v, 1);
      v += __shfl_xor(v, 2);
      v += __shfl_xor(v, 4);
      v += __shfl_xor(v, 8);
      if (l15 == 0) atomicAdd(tr + row0 + tm * 16 + q * 4 + r, -v);
    }
  }
}

extern "C" void kernel_launch(void* const* d_in, const int* in_sizes, int n_in,
                              void* d_out, int out_size, void* d_ws, size_t ws_size,
                              hipStream_t stream) {
  (void)in_sizes; (void)n_in; (void)out_size; (void)ws_size;
  // inputs: t[1], z[B,D], W1[W,D], b1[W], W2[D,W]  (all f32)
  const float* z  = (const float*)d_in[1];
  const float* W1 = (const float*)d_in[2];
  const float* b1 = (const float*)d_in[3];
  const float* W2 = (const float*)d_in[4];
  float* dz = (float*)d_out;                    // [B, D]
  float* tr = dz + (size_t)B_N * D_N;           // [B] = dlogpz_dt (negated trace)

  unsigned short* W1b = (unsigned short*)d_ws;  // 512 KB
  unsigned short* W2b = W1b + (size_t)W_N * D_N; // 512 KB
  float* M = (float*)(W2b + (size_t)W_N * D_N);  // 4 KB

  hipMemsetAsync(tr, 0, B_N * sizeof(float), stream);
  prep_kernel<<<dim3(W_N), dim3(256), 0, stream>>>(W1, W2, W1b, W2b, M);
  flow_kernel<<<dim3(B_N / 64), dim3(256), 0, stream>>>(z, b1, W1b, W2b, M, dz, tr);
}